// Round 1
// baseline (217.907 us; speedup 1.0000x reference)
//
#include <hip/hip_runtime.h>

// MinVarianceWeightsLayer: for each of B SPD 64x64 fp32 matrices S,
// solve S z = 1, output w = z / sum(z) as [B, 64, 1] fp32.
//
// ROUND-9: Gauss-Jordan elimination (replaces LU + back-substitution).
// r8 was latency-bound (VALUBusy ~25%); the 64-step back-sub is a pure
// serial readlane/rcp chain (~1.2k cycles + 380 instrs incl. 128 readlanes).
// Jordan elimination is FREE in this layout: the rank-4 trailing update
// already runs on all 64 lanes with nf masked; switching the mask from
// (lane > k) to (lane != k) eliminates upper rows too at identical
// instruction count. Trailing-submatrix symmetry is preserved (rows > pivot
// evolve exactly as in LU; published columns are only read for trailing
// columns), so the symmetric publish trick still applies. After 64 columns
// the system is diagonal: z = b * rcp(d); d captured per-lane with one
// cndmask per column (el_c at lane k_c IS the pivot).
// Also: publish writes are interleaved into phase 1 (write each el_c as
// soon as it exists) so the LDS write->read round trip overlaps the
// remaining in-panel chain. DS ops are in-order within a wave -> race-free,
// still zero barriers.

#define NN 64

typedef float v2f __attribute__((ext_vector_type(2)));
typedef float v4f __attribute__((ext_vector_type(4)));

template <int I> struct ic { static constexpr int value = I; };

template <int Start, int End, typename F>
__device__ __forceinline__ void static_for(F&& f) {
    if constexpr (Start < End) {
        f(ic<Start>{});
        static_for<Start + 1, End>(static_cast<F&&>(f));
    }
}

__device__ __forceinline__ float rlane(float v, int lane) {
    return __int_as_float(__builtin_amdgcn_readlane(__float_as_int(v), lane));
}

__device__ __forceinline__ float frcp(float x) {
#if __has_builtin(__builtin_amdgcn_rcpf)
    return __builtin_amdgcn_rcpf(x);   // ~1 ulp; plenty vs 2e-3 abs threshold
#else
    return 1.0f / x;
#endif
}

__device__ __forceinline__ v2f fma2(v2f a, v2f b, v2f c) {
#if __has_builtin(__builtin_elementwise_fma)
    return __builtin_elementwise_fma(a, b, c);   // -> v_pk_fma_f32
#else
    v2f r; r.x = fmaf(a.x, b.x, c.x); r.y = fmaf(a.y, b.y, c.y); return r;
#endif
}

__global__ __launch_bounds__(256) void minvar_kernel(const float* __restrict__ sigma,
                                                     float* __restrict__ out,
                                                     int batch) {
    // [wave][panel parity][ m*8 + c*2 + par ] : u_c[2m+par]
    __shared__ float pb[4][2][2 * NN * 4 / 2];   // 4 waves x 2 x 256 floats = 8 KB

    const int lane = threadIdx.x & 63;
    const int wid  = threadIdx.x >> 6;     // 4 waves/block, 1 matrix each
    const int bid  = blockIdx.x * 4 + wid;
    if (bid >= batch) return;              // no barriers anywhere -> safe

    const float* __restrict__ p = sigma + (size_t)bid * (NN * NN) + (size_t)lane * NN;

    // lane i's row as 32 float2 pairs (all indices compile-time -> VGPRs)
    v2f r[NN / 2];
    static_for<0, NN / 4>([&](auto j4c) {
        constexpr int j4 = decltype(j4c)::value;
        v4f v = reinterpret_cast<const v4f*>(p)[j4];
        r[2 * j4 + 0] = v2f{v.x, v.y};
        r[2 * j4 + 1] = v2f{v.z, v.w};
    });

    float b = 1.0f;                        // RHS: ones
    float d = 1.0f;                        // this lane's pivot (set exactly once)
    const int wbase = (lane >> 1) * 8 + (lane & 1);   // scatter-write index

    static_for<0, 16>([&](auto pc) {
        constexpr int P  = decltype(pc)::value;
        constexpr int k0 = 4 * P;
        constexpr int m0 = 2 * P;          // pair-slots m0, m0+1 are the panel
        float* __restrict__ wb = &pb[wid][P & 1][0];

        // ---- phase 1: in-panel Jordan elimination (readlane only, local) ----
        const float el0  = r[m0].x;                    // A[i][k0] (pre-panel)
        if constexpr (P < 15) wb[wbase + 0] = el0;     // publish early
        const float piv0 = rlane(el0, k0);
        const float nf0  = (lane != k0) ? (-el0 * frcp(piv0)) : 0.0f;
        d = (lane == k0) ? el0 : d;
        b = fmaf(nf0, rlane(b, k0), b);
        const float u01 = rlane(r[m0].y,     k0);
        const float u02 = rlane(r[m0 + 1].x, k0);
        const float u03 = rlane(r[m0 + 1].y, k0);
        r[m0].y     = fmaf(nf0, u01, r[m0].y);
        r[m0 + 1].x = fmaf(nf0, u02, r[m0 + 1].x);
        r[m0 + 1].y = fmaf(nf0, u03, r[m0 + 1].y);

        const float el1  = r[m0].y;                    // A[i][k0+1] after c0
        if constexpr (P < 15) wb[wbase + 2] = el1;
        const float piv1 = rlane(el1, k0 + 1);
        const float nf1  = (lane != k0 + 1) ? (-el1 * frcp(piv1)) : 0.0f;
        d = (lane == k0 + 1) ? el1 : d;
        b = fmaf(nf1, rlane(b, k0 + 1), b);
        const float u12 = rlane(r[m0 + 1].x, k0 + 1);
        const float u13 = rlane(r[m0 + 1].y, k0 + 1);
        r[m0 + 1].x = fmaf(nf1, u12, r[m0 + 1].x);
        r[m0 + 1].y = fmaf(nf1, u13, r[m0 + 1].y);

        const float el2  = r[m0 + 1].x;                // A[i][k0+2] after c0,c1
        if constexpr (P < 15) wb[wbase + 4] = el2;
        const float piv2 = rlane(el2, k0 + 2);
        const float nf2  = (lane != k0 + 2) ? (-el2 * frcp(piv2)) : 0.0f;
        d = (lane == k0 + 2) ? el2 : d;
        b = fmaf(nf2, rlane(b, k0 + 2), b);
        const float u23 = rlane(r[m0 + 1].y, k0 + 2);
        r[m0 + 1].y = fmaf(nf2, u23, r[m0 + 1].y);

        const float el3  = r[m0 + 1].y;                // A[i][k0+3] after c0..c2
        if constexpr (P < 15) wb[wbase + 6] = el3;
        const float piv3 = rlane(el3, k0 + 3);
        const float nf3  = (lane != k0 + 3) ? (-el3 * frcp(piv3)) : 0.0f;
        d = (lane == k0 + 3) ? el3 : d;
        b = fmaf(nf3, rlane(b, k0 + 3), b);

        if constexpr (P < 15) {
            // ---- phase 3: rank-4 update of trailing pair-slots (all lanes) ----
            const v2f n0 = v2f{nf0, nf0}, n1 = v2f{nf1, nf1};
            const v2f n2 = v2f{nf2, nf2}, n3 = v2f{nf3, nf3};
            static_for<m0 + 2, NN / 2>([&](auto mc) {
                constexpr int m = decltype(mc)::value;
                const v4f lo = *reinterpret_cast<const v4f*>(wb + 8 * m);     // u0,u1 pairs
                const v4f hi = *reinterpret_cast<const v4f*>(wb + 8 * m + 4); // u2,u3 pairs
                v2f acc = r[m];
                acc = fma2(n0, v2f{lo.x, lo.y}, acc);
                acc = fma2(n1, v2f{lo.z, lo.w}, acc);
                acc = fma2(n2, v2f{hi.x, hi.y}, acc);
                acc = fma2(n3, v2f{hi.z, hi.w}, acc);
                r[m] = acc;
            });
        }
    });

    // ---- diagonal system: z = b / d (no back-substitution in Gauss-Jordan) ----
    const float z = b * frcp(d);

    // ---- normalize: w = z / sum(z) ----
    float tot = z;
    #pragma unroll
    for (int off = 32; off >= 1; off >>= 1)
        tot += __shfl_xor(tot, off, 64);

    out[(size_t)bid * NN + lane] = z * frcp(tot);
}

extern "C" void kernel_launch(void* const* d_in, const int* in_sizes, int n_in,
                              void* d_out, int out_size, void* d_ws, size_t ws_size,
                              hipStream_t stream) {
    const float* sigma = (const float*)d_in[0];
    float* out = (float*)d_out;
    const int batch  = in_sizes[0] / (NN * NN);   // 8192
    const int blocks = (batch + 3) / 4;           // 4 matrices per 256-thr block
    minvar_kernel<<<blocks, 256, 0, stream>>>(sigma, out, batch);
}